// Round 7
// baseline (120.965 us; speedup 1.0000x reference)
//
#include <hip/hip_runtime.h>

#define HH 1024
#define WW 1024
#define BB 8
#define WORDS_X 16             /* 64-px bit-words per row */

typedef unsigned long long u64;
typedef float f4 __attribute__((ext_vector_type(4)));

// ---------------------------------------------------------------------------
// Kernel 1: pack target (int32 0/1) into a bit image. Per wave: 8 independent
// coalesced 256B loads -> 8 ballots -> one 64B store. Unchanged.
// ---------------------------------------------------------------------------
__global__ __launch_bounds__(256) void ls_pack(const int* __restrict__ tgt,
                                               u64* __restrict__ bits) {
    const int lane = threadIdx.x & 63;
    const size_t wv = ((size_t)blockIdx.x * 256 + threadIdx.x) >> 6;
    const size_t wbase = wv * 8;                 // first of 8 words (512 px)
    const int* p = tgt + wbase * 64 + lane;

    int v[8];
#pragma unroll
    for (int j = 0; j < 8; ++j) v[j] = p[j * 64];

    u64 mine = 0;
#pragma unroll
    for (int j = 0; j < 8; ++j) {
        u64 m = __ballot(v[j] != 0);
        if (lane == j) mine = m;
    }
    if (lane < 8) bits[wbase + lane] = mine;
}

// ---------------------------------------------------------------------------
// Kernel 2: edge words from bit image (1MB -> 1MB, L2/L3-resident).
//   t_c=0: edge <=> OR of 11x11 window ; t_c=1: edge <=> !(AND of window)
// (exactly 121*t_c != window_sum with zero padding: OOB rows/words = 0.)
// ---------------------------------------------------------------------------
__global__ __launch_bounds__(256) void ls_edge(const u64* __restrict__ bits,
                                               u64* __restrict__ ebits) {
    __shared__ u64 s_b[26][17], s_oh[26][17], s_ah[26][17];  // +1 pad
    const int tid  = threadIdx.x;
    const int slab = blockIdx.x;      // 0..63
    const int b    = blockIdx.y;      // 0..7
    const int y0   = slab << 4;

#pragma unroll
    for (int i = tid; i < 416; i += 256) {
        int r = i >> 4, k = i & 15;
        int gy = y0 - 5 + r;
        u64 v = 0;
        if ((unsigned)gy < HH) v = bits[((size_t)(b << 10) + gy) * WORDS_X + k];
        s_b[r][k] = v;
    }
    __syncthreads();

#pragma unroll
    for (int i = tid; i < 416; i += 256) {
        int r = i >> 4, k = i & 15;
        u64 wm = s_b[r][k];
        u64 wl = k ? s_b[r][k - 1] : 0;
        u64 wr = (k < 15) ? s_b[r][k + 1] : 0;
        u64 oh = wm, ah = wm;
#pragma unroll
        for (int d = 1; d <= 5; ++d) {
            u64 vr = (wm >> d) | (wr << (64 - d));
            u64 vl = (wm << d) | (wl >> (64 - d));
            oh |= vr | vl;
            ah &= vr & vl;
        }
        s_oh[r][k] = oh;
        s_ah[r][k] = ah;
    }
    __syncthreads();

    {
        int r = tid >> 4, k = tid & 15;   // r: 0..15 within slab
        u64 ov = 0, av = ~0ULL;
#pragma unroll
        for (int j = 0; j < 11; ++j) { ov |= s_oh[r + j][k]; av &= s_ah[r + j][k]; }
        u64 tc = s_b[r + 5][k];
        ebits[((size_t)(b << 10) + y0 + r) * WORDS_X + k] = (ov & ~tc) | (~av & tc);
    }
}

// ---------------------------------------------------------------------------
// Kernel 3: DEEP software-pipelined loss.
// R6 lesson: depth-1 prefetch with 4 iters gained 3us -- right axis, but the
// pipeline never reaches steady state (iter 0 = cold ~900cy stall, done after
// 3 more). This version: 1024 blocks (4/CU, 16 waves/CU), 8 iters/thread
// (block B = row y=B of all 8 batches; all strides compile-time const),
// DEPTH-2 prefetch: two full iterations of loads (2 f4 + 2 broadcast u64
// each) in flight at all times -> ~4KB/wave, 64KB/CU in flight (>22KB needed
// for 6.3 TB/s), and 8-deep loop amortizes the cold start.
// Rotating 2-slot register arrays with it&1 under full unroll: all indices
// compile-time (no scratch). Per-pixel math BIT-IDENTICAL; only summation
// order changes (proven safe: absmax stayed 0.0 across R2->R3->R5 regroups).
// NO device fences / cross-block atomics (r7/r8/r10 lessons).
// ---------------------------------------------------------------------------
__global__ __launch_bounds__(256) void ls_loss5(const float* __restrict__ x,
                                                const u64* __restrict__ bits,
                                                const u64* __restrict__ ebits,
                                                float* __restrict__ partial) {
    __shared__ float s_red[4];
    const int tid = threadIdx.x;
    const int B   = blockIdx.x;               // 0..1023 == row y
    const f4* X = (const f4*)x;
    // iter it = batch b: ch0 f4 index = (b<<19) + y*256 + tid ; ch1 = +(1<<18)
    const size_t base4 = (size_t)B * 256 + tid;
    // mask word index = (b<<14) + y*16 + (tid>>4)
    const size_t mbase = (size_t)B * WORDS_X + (tid >> 4);
    const int sh = (tid & 15) << 2;           // nibble position, const

    f4 a0[2], a1[2]; u64 tw[2], ew[2];
#pragma unroll
    for (int k = 0; k < 2; ++k) {             // prologue: issue it=0,1
        const size_t r4 = base4 + ((size_t)k << 19);
        a0[k] = X[r4];
        a1[k] = X[r4 + (1 << 18)];
        const size_t mb = mbase + ((size_t)k << 14);
        tw[k] = bits[mb];
        ew[k] = ebits[mb];
    }

    float acc = 0.f;
#pragma unroll
    for (int it = 0; it < 8; ++it) {
        const int cur = it & 1;               // compile-time under unroll
        const f4  c0 = a0[cur], c1 = a1[cur];
        const u64 ct = tw[cur], ce = ew[cur];
        if (it < 6) {                         // prefetch it+2 into freed slot
            const size_t r4 = base4 + ((size_t)(it + 2) << 19);
            a0[cur] = X[r4];
            a1[cur] = X[r4 + (1 << 18)];
            const size_t mb = mbase + ((size_t)(it + 2) << 14);
            tw[cur] = bits[mb];
            ew[cur] = ebits[mb];
        }
        const unsigned t4 = (unsigned)(ct >> sh) & 0xfu;
        const unsigned e4 = (unsigned)(ce >> sh) & 0xfu;
#pragma unroll
        for (int j = 0; j < 4; ++j) {
            int t = (t4 >> j) & 1;
            int e = (e4 >> j) & 1;
            float v0 = c0[j], v1 = c1[j];
            float m   = fmaxf(v0, v1);
            float lse = m + __logf(1.0f + __expf(-fabsf(v0 - v1)));
            float lp0 = v0 - lse, lp1 = v1 - lse;
            float lpt = t ? lp1 : lp0;
            float lpo = t ? lp0 : lp1;
            acc += e ? (0.95f * lpt + 0.1f * lpo) : lpt;
        }
    }

#pragma unroll
    for (int off = 32; off > 0; off >>= 1) acc += __shfl_down(acc, off, 64);
    if ((tid & 63) == 0) s_red[tid >> 6] = acc;
    __syncthreads();
    if (tid == 0)
        partial[B] = s_red[0] + s_red[1] + s_red[2] + s_red[3];
}

__global__ __launch_bounds__(1024) void ls_final(const float* __restrict__ partial,
                                                 float* __restrict__ out) {
    __shared__ double s_red[16];
    const int tid = threadIdx.x;
    double s = (double)partial[tid];          // 1024 partials, one per row y
#pragma unroll
    for (int off = 32; off > 0; off >>= 1) s += __shfl_down(s, off, 64);
    if ((tid & 63) == 0) s_red[tid >> 6] = s;
    __syncthreads();
    if (tid == 0) {
        double total = 0.0;
#pragma unroll
        for (int i = 0; i < 16; ++i) total += s_red[i];
        out[0] = (float)(-total * (1.0 / (8.0 * 1024.0 * 1024.0)));
    }
}

extern "C" void kernel_launch(void* const* d_in, const int* in_sizes, int n_in,
                              void* d_out, int out_size, void* d_ws, size_t ws_size,
                              hipStream_t stream) {
    const float* x  = (const float*)d_in[0];
    const int* tgt  = (const int*)d_in[1];

    // ws: [partials 32KB][bits @64KB, 1MB][ebits @64KB+1MB, 1MB]
    float* partial = (float*)d_ws;
    u64* bits  = (u64*)((char*)d_ws + (64 << 10));
    u64* ebits = (u64*)((char*)d_ws + (64 << 10) + (1 << 20));

    hipLaunchKernelGGL(ls_pack, dim3(4096), dim3(256), 0, stream, tgt, bits);
    hipLaunchKernelGGL(ls_edge, dim3(64, 8), dim3(256), 0, stream, bits, ebits);
    hipLaunchKernelGGL(ls_loss5, dim3(1024), dim3(256), 0, stream, x, bits, ebits, partial);
    hipLaunchKernelGGL(ls_final, dim3(1), dim3(1024), 0, stream, partial, (float*)d_out);
}

// Round 8
// 119.296 us; speedup vs baseline: 1.0140x; 1.0140x over previous
//
#include <hip/hip_runtime.h>

#define HH 1024
#define WW 1024
#define BB 8
#define WORDS_X 16             /* 64-px bit-words per row */

typedef unsigned long long u64;
typedef float f4 __attribute__((ext_vector_type(4)));

// ---------------------------------------------------------------------------
// Kernel 1: pack target (int32 0/1) into a bit image. Per wave: 8 independent
// coalesced 256B loads -> 8 ballots -> one 64B store. Unchanged.
// ---------------------------------------------------------------------------
__global__ __launch_bounds__(256) void ls_pack(const int* __restrict__ tgt,
                                               u64* __restrict__ bits) {
    const int lane = threadIdx.x & 63;
    const size_t wv = ((size_t)blockIdx.x * 256 + threadIdx.x) >> 6;
    const size_t wbase = wv * 8;                 // first of 8 words (512 px)
    const int* p = tgt + wbase * 64 + lane;

    int v[8];
#pragma unroll
    for (int j = 0; j < 8; ++j) v[j] = p[j * 64];

    u64 mine = 0;
#pragma unroll
    for (int j = 0; j < 8; ++j) {
        u64 m = __ballot(v[j] != 0);
        if (lane == j) mine = m;
    }
    if (lane < 8) bits[wbase + lane] = mine;
}

// ---------------------------------------------------------------------------
// Kernel 2: edge words from bit image (1MB -> 1MB, L2/L3-resident).
//   t_c=0: edge <=> OR of 11x11 window ; t_c=1: edge <=> !(AND of window)
// (exactly 121*t_c != window_sum with zero padding: OOB rows/words = 0.)
// ---------------------------------------------------------------------------
__global__ __launch_bounds__(256) void ls_edge(const u64* __restrict__ bits,
                                               u64* __restrict__ ebits) {
    __shared__ u64 s_b[26][17], s_oh[26][17], s_ah[26][17];  // +1 pad
    const int tid  = threadIdx.x;
    const int slab = blockIdx.x;      // 0..63
    const int b    = blockIdx.y;      // 0..7
    const int y0   = slab << 4;

#pragma unroll
    for (int i = tid; i < 416; i += 256) {
        int r = i >> 4, k = i & 15;
        int gy = y0 - 5 + r;
        u64 v = 0;
        if ((unsigned)gy < HH) v = bits[((size_t)(b << 10) + gy) * WORDS_X + k];
        s_b[r][k] = v;
    }
    __syncthreads();

#pragma unroll
    for (int i = tid; i < 416; i += 256) {
        int r = i >> 4, k = i & 15;
        u64 wm = s_b[r][k];
        u64 wl = k ? s_b[r][k - 1] : 0;
        u64 wr = (k < 15) ? s_b[r][k + 1] : 0;
        u64 oh = wm, ah = wm;
#pragma unroll
        for (int d = 1; d <= 5; ++d) {
            u64 vr = (wm >> d) | (wr << (64 - d));
            u64 vl = (wm << d) | (wl >> (64 - d));
            oh |= vr | vl;
            ah &= vr & vl;
        }
        s_oh[r][k] = oh;
        s_ah[r][k] = ah;
    }
    __syncthreads();

    {
        int r = tid >> 4, k = tid & 15;   // r: 0..15 within slab
        u64 ov = 0, av = ~0ULL;
#pragma unroll
        for (int j = 0; j < 11; ++j) { ov |= s_oh[r + j][k]; av &= s_ah[r + j][k]; }
        u64 tc = s_b[r + 5][k];
        ebits[((size_t)(b << 10) + y0 + r) * WORDS_X + k] = (ov & ~tc) | (~av & tc);
    }
}

// ---------------------------------------------------------------------------
// Kernel 3: R6 geometry + DEPTH-2 pipeline (single-variable change vs R6).
// R6 (2048 blk, 4 iters, depth-1) = best, 119.18. R7 (1024 blk, 8 iters,
// depth-2) = 120.97 -- but confounded (halved TLP). This: 2048 blocks
// (8/CU, 32 waves/CU), 4 iters/thread, depth-2 prefetch: prologue issues
// iters 0+1 (2x in-flight bytes of R6 at identical TLP), loop prefetches
// it+2. All strides compile-time const; rotating 2-slot arrays with it&1
// under full unroll (rule-#20 safe, proven in R7 compile).
// Per-pixel math BIT-IDENTICAL; summation order proven safe (absmax 0.0
// across R2/R3/R5/R6/R7 regroupings).
// NO device fences / cross-block atomics (r7/r8/r10 lessons).
// ---------------------------------------------------------------------------
__global__ __launch_bounds__(256, 8) void ls_loss6(const float* __restrict__ x,
                                                   const u64* __restrict__ bits,
                                                   const u64* __restrict__ ebits,
                                                   float* __restrict__ partial) {
    __shared__ float s_red[4];
    const int tid = threadIdx.x;
    const int B   = blockIdx.x;          // 0..2047
    const int y   = B & 1023;
    const int b0  = B >> 10;             // 0 or 1
    // iteration it: batch b = b0 + 2*it, same row y.
    const f4* X = (const f4*)x;
    const size_t base4 = (size_t)b0 * 524288 + (size_t)y * 256 + tid; // ch0 f4 idx
    const size_t mbase = (size_t)B * WORDS_X + (tid >> 4);
    const int sh = (tid & 15) << 2;      // nibble position, const per thread

    f4 a0[2], a1[2]; u64 tw[2], ew[2];
#pragma unroll
    for (int k = 0; k < 2; ++k) {        // prologue: issue it=0 and it=1
        const size_t r4 = base4 + (size_t)k * 1048576;
        a0[k] = X[r4];
        a1[k] = X[r4 + 262144];
        const size_t mb = mbase + (size_t)k * 32768;
        tw[k] = bits[mb];
        ew[k] = ebits[mb];
    }

    float acc = 0.f;
#pragma unroll
    for (int it = 0; it < 4; ++it) {
        const int cur = it & 1;          // compile-time under unroll
        const f4  c0 = a0[cur], c1 = a1[cur];
        const u64 ct = tw[cur], ce = ew[cur];
        if (it < 2) {                    // prefetch it+2 into freed slot
            const size_t r4 = base4 + (size_t)(it + 2) * 1048576;
            a0[cur] = X[r4];
            a1[cur] = X[r4 + 262144];
            const size_t mb = mbase + (size_t)(it + 2) * 32768;
            tw[cur] = bits[mb];
            ew[cur] = ebits[mb];
        }
        const unsigned t4 = (unsigned)(ct >> sh) & 0xfu;
        const unsigned e4 = (unsigned)(ce >> sh) & 0xfu;
#pragma unroll
        for (int j = 0; j < 4; ++j) {
            int t = (t4 >> j) & 1;
            int e = (e4 >> j) & 1;
            float v0 = c0[j], v1 = c1[j];
            float m   = fmaxf(v0, v1);
            float lse = m + __logf(1.0f + __expf(-fabsf(v0 - v1)));
            float lp0 = v0 - lse, lp1 = v1 - lse;
            float lpt = t ? lp1 : lp0;
            float lpo = t ? lp0 : lp1;
            acc += e ? (0.95f * lpt + 0.1f * lpo) : lpt;
        }
    }

#pragma unroll
    for (int off = 32; off > 0; off >>= 1) acc += __shfl_down(acc, off, 64);
    if ((tid & 63) == 0) s_red[tid >> 6] = acc;
    __syncthreads();
    if (tid == 0)
        partial[B] = s_red[0] + s_red[1] + s_red[2] + s_red[3];
}

__global__ __launch_bounds__(1024) void ls_final(const float* __restrict__ partial,
                                                 float* __restrict__ out) {
    __shared__ double s_red[16];
    const int tid = threadIdx.x;
    double s = (double)partial[tid] + (double)partial[tid + 1024];
#pragma unroll
    for (int off = 32; off > 0; off >>= 1) s += __shfl_down(s, off, 64);
    if ((tid & 63) == 0) s_red[tid >> 6] = s;
    __syncthreads();
    if (tid == 0) {
        double total = 0.0;
#pragma unroll
        for (int i = 0; i < 16; ++i) total += s_red[i];
        out[0] = (float)(-total * (1.0 / (8.0 * 1024.0 * 1024.0)));
    }
}

extern "C" void kernel_launch(void* const* d_in, const int* in_sizes, int n_in,
                              void* d_out, int out_size, void* d_ws, size_t ws_size,
                              hipStream_t stream) {
    const float* x  = (const float*)d_in[0];
    const int* tgt  = (const int*)d_in[1];

    // ws: [partials 32KB][bits @64KB, 1MB][ebits @64KB+1MB, 1MB]
    float* partial = (float*)d_ws;
    u64* bits  = (u64*)((char*)d_ws + (64 << 10));
    u64* ebits = (u64*)((char*)d_ws + (64 << 10) + (1 << 20));

    hipLaunchKernelGGL(ls_pack, dim3(4096), dim3(256), 0, stream, tgt, bits);
    hipLaunchKernelGGL(ls_edge, dim3(64, 8), dim3(256), 0, stream, bits, ebits);
    hipLaunchKernelGGL(ls_loss6, dim3(2048), dim3(256), 0, stream, x, bits, ebits, partial);
    hipLaunchKernelGGL(ls_final, dim3(1), dim3(1024), 0, stream, partial, (float*)d_out);
}